// Round 3
// baseline (431.426 us; speedup 1.0000x reference)
//
#include <hip/hip_runtime.h>

#define VOCAB 5000

typedef float f32x4 __attribute__((ext_vector_type(4)));

// ---------------------------------------------------------------------------
// Counting sort of positions by token id.
// ---------------------------------------------------------------------------
__global__ void zero_kernel(int* __restrict__ ptr, int n) {
    int i = blockIdx.x * blockDim.x + threadIdx.x;
    if (i < n) ptr[i] = 0;
}

__global__ void hist_kernel(const int* __restrict__ x, int* __restrict__ counts, int n) {
    int i = blockIdx.x * blockDim.x + threadIdx.x;
    if (i < n) atomicAdd(&counts[x[i]], 1);
}

// Single-block exclusive scan over VOCAB counters -> offs[0..VOCAB].
__global__ void scan_kernel(const int* __restrict__ counts, int* __restrict__ offs) {
    __shared__ int part[1024];
    const int tid = threadIdx.x;
    const int base = tid * 5;               // 1024*5 = 5120 >= 5000
    int local[5];
    int sum = 0;
#pragma unroll
    for (int k = 0; k < 5; ++k) {
        int idx = base + k;
        int v = (idx < VOCAB) ? counts[idx] : 0;
        local[k] = sum;
        sum += v;
    }
    part[tid] = sum;
    __syncthreads();
    for (int off = 1; off < 1024; off <<= 1) {
        int v = 0;
        if (tid >= off) v = part[tid - off];
        __syncthreads();
        if (tid >= off) part[tid] += v;
        __syncthreads();
    }
    const int prev = (tid > 0) ? part[tid - 1] : 0;
#pragma unroll
    for (int k = 0; k < 5; ++k) {
        int idx = base + k;
        if (idx < VOCAB) offs[idx] = prev + local[k];
    }
    if (tid == 1023) offs[VOCAB] = part[1023];
}

__global__ void scatter_kernel(const int* __restrict__ x, const int* __restrict__ offs,
                               int* __restrict__ cursor, int* __restrict__ sorted_pos, int n) {
    int i = blockIdx.x * blockDim.x + threadIdx.x;
    if (i < n) {
        int t = x[i];
        int d = atomicAdd(&cursor[t], 1);
        sorted_pos[offs[t] + d] = i;
    }
}

// ---------------------------------------------------------------------------
// Fused transpose + broadcast gather.
// Block (jg, tg) owns W cols j0..j0+31 (output cols) x tokens t0..t0+31.
// Loads the 32x32 W tile coalesced (transposing into LDS), then writes the
// 32-float row segment to every output position whose token is in the tile
// (contiguous range of the sorted position list).
// Each W line is read exactly once device-wide; out written once, NT.
// ---------------------------------------------------------------------------
__global__ void fused_gather_kernel(const float* __restrict__ W,
                                    const int* __restrict__ x,
                                    const int* __restrict__ offs,
                                    const int* __restrict__ sorted_pos,
                                    float* __restrict__ out) {
    __shared__ float tileT[32][36];   // [token][col], pad 36: f4 reads 16B-aligned
    const int j0 = blockIdx.x * 32;
    const int t0 = blockIdx.y * 32;
    const int jcnt = min(32, VOCAB - j0);   // 32 or 8 (5000 % 32 == 8)
    const int tcnt = min(32, VOCAB - t0);
    const int tx = threadIdx.x & 31;
    const int ty = threadIdx.x >> 5;        // 0..7

#pragma unroll
    for (int k = 0; k < 4; ++k) {
        int r = ty + k * 8;                 // col offset within j-group
        if (r < jcnt && tx < tcnt)
            tileT[tx][r] = W[(size_t)(j0 + r) * VOCAB + t0 + tx];
    }
    __syncthreads();

    const int begin = offs[t0];
    const int end   = offs[t0 + tcnt];
    const int nch   = jcnt >> 2;            // float4 chunks: 8 or 2
    const int slot  = threadIdx.x >> 3;     // 0..31 position slot
    const int c4    = threadIdx.x & 7;      // 0..7 float4 chunk

    for (int i = begin + slot; i < end; i += 32) {
        int p  = sorted_pos[i];
        int tt = x[p] - t0;
        if (c4 < nch) {
            f32x4 v = *reinterpret_cast<const f32x4*>(&tileT[tt][c4 * 4]);
            __builtin_nontemporal_store(
                v, reinterpret_cast<f32x4*>(out + (size_t)p * VOCAB + j0 + c4 * 4));
        }
    }
}

// ---------------------------------------------------------------------------
// Fallback (ws too small): direct column gather, correct but strided reads.
// ---------------------------------------------------------------------------
__global__ void gather_cols_kernel(const float* __restrict__ W,
                                   const int* __restrict__ idx,
                                   float* __restrict__ out) {
    const int p = blockIdx.x;
    const int token = idx[p];
    for (int v = threadIdx.x; v < VOCAB; v += blockDim.x)
        out[(size_t)p * VOCAB + v] = W[(size_t)v * VOCAB + token];
}

extern "C" void kernel_launch(void* const* d_in, const int* in_sizes, int n_in,
                              void* d_out, int out_size, void* d_ws, size_t ws_size,
                              hipStream_t stream) {
    const int*   x = (const int*)d_in[0];     // [B*T] token ids
    const float* W = (const float*)d_in[1];   // [VOCAB, VOCAB] fp32
    float* out = (float*)d_out;               // [B*T, VOCAB] fp32
    const int npos = in_sizes[0];             // 32768

    // ws layout: counts[V] | cursor[V] | offs[V+1] | sorted_pos[npos]
    int* counts = (int*)d_ws;
    int* cursor = counts + VOCAB;
    int* offs   = cursor + VOCAB;
    int* sorted = offs + VOCAB + 1;
    const size_t need = (size_t)(2 * VOCAB + VOCAB + 1 + npos) * sizeof(int);

    if (ws_size >= need) {
        zero_kernel<<<(2 * VOCAB + 255) / 256, 256, 0, stream>>>(counts, 2 * VOCAB);
        hist_kernel<<<(npos + 255) / 256, 256, 0, stream>>>(x, counts, npos);
        scan_kernel<<<1, 1024, 0, stream>>>(counts, offs);
        scatter_kernel<<<(npos + 255) / 256, 256, 0, stream>>>(x, offs, cursor, sorted, npos);
        dim3 grid((VOCAB + 31) / 32, (VOCAB + 31) / 32);
        fused_gather_kernel<<<grid, 256, 0, stream>>>(W, x, offs, sorted, out);
    } else {
        gather_cols_kernel<<<npos, 256, 0, stream>>>(W, x, out);
    }
}

// Round 4
// 202.506 us; speedup vs baseline: 2.1304x; 2.1304x over previous
//
#include <hip/hip_runtime.h>

#define VOCAB 5000
#define TTOK  16            // tokens per tile (64B line = 16 floats, read-once)
#define JCH   512           // output cols per chunk
#define LSTR  516           // LDS row stride (pad 4; 516*4 % 16 == 0, 516 % 32 == 4)

typedef float f32x4 __attribute__((ext_vector_type(4)));

// ---------------------------------------------------------------------------
// Counting sort of positions by token id (packed: (pos << 13) | token).
// ---------------------------------------------------------------------------
__global__ void zero_kernel(int* __restrict__ ptr, int n) {
    int i = blockIdx.x * blockDim.x + threadIdx.x;
    if (i < n) ptr[i] = 0;
}

__global__ void hist_kernel(const int* __restrict__ x, int* __restrict__ counts, int n) {
    int i = blockIdx.x * blockDim.x + threadIdx.x;
    if (i < n) atomicAdd(&counts[x[i]], 1);
}

// Single-block exclusive scan over VOCAB counters -> offs[0..VOCAB].
__global__ void scan_kernel(const int* __restrict__ counts, int* __restrict__ offs) {
    __shared__ int part[1024];
    const int tid = threadIdx.x;
    const int base = tid * 5;               // 1024*5 = 5120 >= 5000
    int local[5];
    int sum = 0;
#pragma unroll
    for (int k = 0; k < 5; ++k) {
        int idx = base + k;
        int v = (idx < VOCAB) ? counts[idx] : 0;
        local[k] = sum;
        sum += v;
    }
    part[tid] = sum;
    __syncthreads();
    for (int off = 1; off < 1024; off <<= 1) {
        int v = 0;
        if (tid >= off) v = part[tid - off];
        __syncthreads();
        if (tid >= off) part[tid] += v;
        __syncthreads();
    }
    const int prev = (tid > 0) ? part[tid - 1] : 0;
#pragma unroll
    for (int k = 0; k < 5; ++k) {
        int idx = base + k;
        if (idx < VOCAB) offs[idx] = prev + local[k];
    }
    if (tid == 1023) offs[VOCAB] = part[1023];
}

__global__ void scatter_kernel(const int* __restrict__ x, const int* __restrict__ offs,
                               int* __restrict__ cursor, int* __restrict__ sorted_pk, int n) {
    int i = blockIdx.x * blockDim.x + threadIdx.x;
    if (i < n) {
        int t = x[i];
        int d = atomicAdd(&cursor[t], 1);
        sorted_pk[offs[t] + d] = (i << 13) | t;   // pos (15b) | token (13b)
    }
}

// ---------------------------------------------------------------------------
// Fused transpose + broadcast gather.
// Block (jc, tg): W cols j0..j0+511 (output cols) x tokens t0..t0+15.
// Tile loaded coalesced (64B row segments), transposed into LDS.
// Each position whose token is in the tile gets a 2KB contiguous NT write
// (2 x 1KB wave-stores). Each W line read exactly once device-wide.
// ---------------------------------------------------------------------------
__global__ __launch_bounds__(256) void fused_gather_kernel(
        const float* __restrict__ W,
        const int* __restrict__ offs,
        const int* __restrict__ sorted_pk,
        float* __restrict__ out) {
    __shared__ float tileT[TTOK][LSTR];
    const int j0 = blockIdx.x * JCH;
    const int t0 = blockIdx.y * TTOK;
    const int jcnt = min(JCH, VOCAB - j0);    // 512 or 392
    const int tcnt = min(TTOK, VOCAB - t0);   // 16 or 8
    const int tid = threadIdx.x;

    const int begin = offs[t0];
    const int end   = offs[t0 + tcnt];
    if (begin == end) return;                 // no positions use these tokens

    // --- load tile, transposed: tileT[token][col] ---
    const int nc4  = tcnt >> 2;               // f32x4 chunks across tokens: 4 or 2
    const int csh  = (tcnt == TTOK) ? 2 : 1;
    const int cmask = nc4 - 1;
    const int total = jcnt * nc4;
    for (int idx = tid; idx < total; idx += 256) {
        const int jr = idx >> csh;
        const int c  = idx & cmask;
        f32x4 v = *reinterpret_cast<const f32x4*>(
            W + (size_t)(j0 + jr) * VOCAB + t0 + c * 4);
        tileT[c * 4 + 0][jr] = v.x;
        tileT[c * 4 + 1][jr] = v.y;
        tileT[c * 4 + 2][jr] = v.z;
        tileT[c * 4 + 3][jr] = v.w;
    }
    __syncthreads();

    // --- broadcast write: one position per wave per iteration ---
    const int wid  = tid >> 6;
    const int lane = tid & 63;
    const int f0 = lane * 4;
    const int f1 = f0 + 256;
    const bool a0 = (f0 < jcnt);              // always true (f0 <= 252)
    const bool a1 = (f1 < jcnt);

    for (int i = begin + wid; i < end; i += 4) {
        const int pk = sorted_pk[i];
        const int p  = pk >> 13;
        const int tt = (pk & 8191) - t0;
        const float* __restrict__ srow = &tileT[tt][0];
        float* __restrict__ drow = out + (size_t)p * VOCAB + j0;
        if (a0) {
            f32x4 v = *reinterpret_cast<const f32x4*>(srow + f0);
            __builtin_nontemporal_store(v, reinterpret_cast<f32x4*>(drow + f0));
        }
        if (a1) {
            f32x4 v = *reinterpret_cast<const f32x4*>(srow + f1);
            __builtin_nontemporal_store(v, reinterpret_cast<f32x4*>(drow + f1));
        }
    }
}

// ---------------------------------------------------------------------------
// Fallback (ws too small): direct column gather, correct but strided reads.
// ---------------------------------------------------------------------------
__global__ void gather_cols_kernel(const float* __restrict__ W,
                                   const int* __restrict__ idx,
                                   float* __restrict__ out) {
    const int p = blockIdx.x;
    const int token = idx[p];
    for (int v = threadIdx.x; v < VOCAB; v += blockDim.x)
        out[(size_t)p * VOCAB + v] = W[(size_t)v * VOCAB + token];
}

extern "C" void kernel_launch(void* const* d_in, const int* in_sizes, int n_in,
                              void* d_out, int out_size, void* d_ws, size_t ws_size,
                              hipStream_t stream) {
    const int*   x = (const int*)d_in[0];     // [B*T] token ids
    const float* W = (const float*)d_in[1];   // [VOCAB, VOCAB] fp32
    float* out = (float*)d_out;               // [B*T, VOCAB] fp32
    const int npos = in_sizes[0];             // 32768

    // ws layout: counts[V] | cursor[V] | offs[V+1] | sorted_pk[npos]
    int* counts = (int*)d_ws;
    int* cursor = counts + VOCAB;
    int* offs   = cursor + VOCAB;
    int* sorted = offs + VOCAB + 1;
    const size_t need = (size_t)(3 * VOCAB + 1 + npos) * sizeof(int);

    if (ws_size >= need) {
        zero_kernel<<<(2 * VOCAB + 255) / 256, 256, 0, stream>>>(counts, 2 * VOCAB);
        hist_kernel<<<(npos + 255) / 256, 256, 0, stream>>>(x, counts, npos);
        scan_kernel<<<1, 1024, 0, stream>>>(counts, offs);
        scatter_kernel<<<(npos + 255) / 256, 256, 0, stream>>>(x, offs, cursor, sorted, npos);
        dim3 grid((VOCAB + JCH - 1) / JCH, (VOCAB + TTOK - 1) / TTOK);  // 10 x 313
        fused_gather_kernel<<<grid, 256, 0, stream>>>(W, offs, sorted, out);
    } else {
        gather_cols_kernel<<<npos, 256, 0, stream>>>(W, x, out);
    }
}

// Round 5
// 198.745 us; speedup vs baseline: 2.1708x; 1.0189x over previous
//
#include <hip/hip_runtime.h>

#define VOCAB 5000
#define TTOK  16            // tokens per tile
#define JCH   512           // output cols per chunk
#define LSTR  516           // LDS row stride (pad 4; keeps f4 reads 16B-aligned)

typedef float f32x4 __attribute__((ext_vector_type(4)));

// ---------------------------------------------------------------------------
// Counting sort of positions by token id (packed: (pos << 13) | token).
// ---------------------------------------------------------------------------
__global__ void zero_kernel(int* __restrict__ ptr, int n) {
    int i = blockIdx.x * blockDim.x + threadIdx.x;
    if (i < n) ptr[i] = 0;
}

__global__ void hist_kernel(const int* __restrict__ x, int* __restrict__ counts, int n) {
    int i = blockIdx.x * blockDim.x + threadIdx.x;
    if (i < n) atomicAdd(&counts[x[i]], 1);
}

// Single-block exclusive scan over VOCAB counters -> offs[0..VOCAB].
__global__ void scan_kernel(const int* __restrict__ counts, int* __restrict__ offs) {
    __shared__ int part[1024];
    const int tid = threadIdx.x;
    const int base = tid * 5;               // 1024*5 = 5120 >= 5000
    int local[5];
    int sum = 0;
#pragma unroll
    for (int k = 0; k < 5; ++k) {
        int idx = base + k;
        int v = (idx < VOCAB) ? counts[idx] : 0;
        local[k] = sum;
        sum += v;
    }
    part[tid] = sum;
    __syncthreads();
    for (int off = 1; off < 1024; off <<= 1) {
        int v = 0;
        if (tid >= off) v = part[tid - off];
        __syncthreads();
        if (tid >= off) part[tid] += v;
        __syncthreads();
    }
    const int prev = (tid > 0) ? part[tid - 1] : 0;
#pragma unroll
    for (int k = 0; k < 5; ++k) {
        int idx = base + k;
        if (idx < VOCAB) offs[idx] = prev + local[k];
    }
    if (tid == 1023) offs[VOCAB] = part[1023];
}

__global__ void scatter_kernel(const int* __restrict__ x, const int* __restrict__ offs,
                               int* __restrict__ cursor, int* __restrict__ sorted_pk, int n) {
    int i = blockIdx.x * blockDim.x + threadIdx.x;
    if (i < n) {
        int t = x[i];
        int d = atomicAdd(&cursor[t], 1);
        sorted_pk[offs[t] + d] = (i << 13) | t;   // pos (15b) | token (13b)
    }
}

// ---------------------------------------------------------------------------
// Fused transpose + broadcast gather.
// Block (jc, tg): W cols j0..j0+511 (output cols) x tokens t0..t0+15.
// Tile loaded coalesced (64B row segments), transposed into LDS.
// Store phase: 8 waves, one position per wave per iteration, 2KB contiguous
// NT write each; pk prefetched one iteration ahead to break the latency chain.
// ---------------------------------------------------------------------------
__global__ __launch_bounds__(512) void fused_gather_kernel(
        const float* __restrict__ W,
        const int* __restrict__ offs,
        const int* __restrict__ sorted_pk,
        float* __restrict__ out) {
    __shared__ float tileT[TTOK][LSTR];
    const int j0 = blockIdx.x * JCH;
    const int t0 = blockIdx.y * TTOK;
    const int jcnt = min(JCH, VOCAB - j0);    // 512 or 392
    const int tcnt = min(TTOK, VOCAB - t0);   // 16 or 8
    const int tid = threadIdx.x;

    const int begin = offs[t0];
    const int end   = offs[t0 + tcnt];
    if (begin == end) return;                 // no positions use these tokens

    // --- load tile, transposed: tileT[token][col] ---
    const int nc4  = tcnt >> 2;               // f32x4 chunks across tokens: 4 or 2
    const int csh  = (tcnt == TTOK) ? 2 : 1;
    const int cmask = nc4 - 1;
    const int total = jcnt * nc4;
    for (int idx = tid; idx < total; idx += 512) {
        const int jr = idx >> csh;
        const int c  = idx & cmask;
        f32x4 v = *reinterpret_cast<const f32x4*>(
            W + (size_t)(j0 + jr) * VOCAB + t0 + c * 4);
        tileT[c * 4 + 0][jr] = v.x;
        tileT[c * 4 + 1][jr] = v.y;
        tileT[c * 4 + 2][jr] = v.z;
        tileT[c * 4 + 3][jr] = v.w;
    }
    __syncthreads();

    // --- broadcast write: 8 waves, one position per wave per iteration ---
    const int wid  = tid >> 6;                // 0..7
    const int lane = tid & 63;
    const int f0 = lane * 4;                  // 0..252
    const int f1 = f0 + 256;                  // 256..508
    const bool a1 = (f1 < jcnt);              // f0 always < jcnt (jcnt >= 392)

    int i  = begin + wid;
    if (i >= end) return;
    int pk = sorted_pk[i];
    for (;;) {
        const int inext = i + 8;
        int pk_next = 0;
        if (inext < end) pk_next = sorted_pk[inext];   // prefetch next position

        const int p  = pk >> 13;
        const int tt = (pk & 8191) - t0;
        const float* __restrict__ srow = &tileT[tt][0];
        float* __restrict__ drow = out + (size_t)p * VOCAB + j0;
        {
            f32x4 v = *reinterpret_cast<const f32x4*>(srow + f0);
            __builtin_nontemporal_store(v, reinterpret_cast<f32x4*>(drow + f0));
        }
        if (a1) {
            f32x4 v = *reinterpret_cast<const f32x4*>(srow + f1);
            __builtin_nontemporal_store(v, reinterpret_cast<f32x4*>(drow + f1));
        }
        if (inext >= end) break;
        i = inext;
        pk = pk_next;
    }
}

// ---------------------------------------------------------------------------
// Fallback (ws too small): direct column gather, correct but strided reads.
// ---------------------------------------------------------------------------
__global__ void gather_cols_kernel(const float* __restrict__ W,
                                   const int* __restrict__ idx,
                                   float* __restrict__ out) {
    const int p = blockIdx.x;
    const int token = idx[p];
    for (int v = threadIdx.x; v < VOCAB; v += blockDim.x)
        out[(size_t)p * VOCAB + v] = W[(size_t)v * VOCAB + token];
}

extern "C" void kernel_launch(void* const* d_in, const int* in_sizes, int n_in,
                              void* d_out, int out_size, void* d_ws, size_t ws_size,
                              hipStream_t stream) {
    const int*   x = (const int*)d_in[0];     // [B*T] token ids
    const float* W = (const float*)d_in[1];   // [VOCAB, VOCAB] fp32
    float* out = (float*)d_out;               // [B*T, VOCAB] fp32
    const int npos = in_sizes[0];             // 32768

    // ws layout: counts[V] | cursor[V] | offs[V+1] | sorted_pk[npos]
    int* counts = (int*)d_ws;
    int* cursor = counts + VOCAB;
    int* offs   = cursor + VOCAB;
    int* sorted = offs + VOCAB + 1;
    const size_t need = (size_t)(3 * VOCAB + 1 + npos) * sizeof(int);

    if (ws_size >= need) {
        zero_kernel<<<(2 * VOCAB + 255) / 256, 256, 0, stream>>>(counts, 2 * VOCAB);
        hist_kernel<<<(npos + 255) / 256, 256, 0, stream>>>(x, counts, npos);
        scan_kernel<<<1, 1024, 0, stream>>>(counts, offs);
        scatter_kernel<<<(npos + 255) / 256, 256, 0, stream>>>(x, offs, cursor, sorted, npos);
        dim3 grid((VOCAB + JCH - 1) / JCH, (VOCAB + TTOK - 1) / TTOK);  // 10 x 313
        fused_gather_kernel<<<grid, 512, 0, stream>>>(W, offs, sorted, out);
    } else {
        gather_cols_kernel<<<npos, 256, 0, stream>>>(W, x, out);
    }
}

// Round 6
// 186.684 us; speedup vs baseline: 2.3110x; 1.0646x over previous
//
#include <hip/hip_runtime.h>

#define VOCAB 5000
#define TTOK  16            // tokens per tile (64B of each W row)
#define JCH   2048          // output cols per chunk -> 8KB contiguous write/visit
#define NTT   313           // ceil(5000/16) token tiles

typedef float f32x4 __attribute__((ext_vector_type(4)));

// ---------------------------------------------------------------------------
// Counting sort of positions by token id (packed: (pos << 13) | token).
// ---------------------------------------------------------------------------
__global__ void zero_kernel(int* __restrict__ ptr, int n) {
    int i = blockIdx.x * blockDim.x + threadIdx.x;
    if (i < n) ptr[i] = 0;
}

__global__ void hist_kernel(const int* __restrict__ x, int* __restrict__ counts, int n) {
    int i = blockIdx.x * blockDim.x + threadIdx.x;
    if (i < n) atomicAdd(&counts[x[i]], 1);
}

// Single-block exclusive scan over VOCAB counters -> offs[0..VOCAB].
__global__ void scan_kernel(const int* __restrict__ counts, int* __restrict__ offs) {
    __shared__ int part[1024];
    const int tid = threadIdx.x;
    const int base = tid * 5;               // 1024*5 = 5120 >= 5000
    int local[5];
    int sum = 0;
#pragma unroll
    for (int k = 0; k < 5; ++k) {
        int idx = base + k;
        int v = (idx < VOCAB) ? counts[idx] : 0;
        local[k] = sum;
        sum += v;
    }
    part[tid] = sum;
    __syncthreads();
    for (int off = 1; off < 1024; off <<= 1) {
        int v = 0;
        if (tid >= off) v = part[tid - off];
        __syncthreads();
        if (tid >= off) part[tid] += v;
        __syncthreads();
    }
    const int prev = (tid > 0) ? part[tid - 1] : 0;
#pragma unroll
    for (int k = 0; k < 5; ++k) {
        int idx = base + k;
        if (idx < VOCAB) offs[idx] = prev + local[k];
    }
    if (tid == 1023) offs[VOCAB] = part[1023];
}

__global__ void scatter_kernel(const int* __restrict__ x, const int* __restrict__ offs,
                               int* __restrict__ cursor, int* __restrict__ sorted_pk, int n) {
    int i = blockIdx.x * blockDim.x + threadIdx.x;
    if (i < n) {
        int t = x[i];
        int d = atomicAdd(&cursor[t], 1);
        sorted_pk[offs[t] + d] = (i << 13) | t;   // pos (15b) | token (13b)
    }
}

// ---------------------------------------------------------------------------
// Fused transpose + broadcast gather.
// Block (cidx, tidx): W cols j0..j0+2047 (output cols) x tokens t0..t0+15.
// LDS tile = 16 x 2048 floats = 128 KiB (1 block/CU, 16 waves).
// Load: coalesced 64B row-segments of W, read exactly once device-wide.
// Store: one position per wave per iteration, 8KB contiguous NT write
// (8 full 1KB wave-stores); pk prefetched one iteration ahead.
// ---------------------------------------------------------------------------
__global__ __launch_bounds__(1024) void fused_gather_kernel(
        const float* __restrict__ W,
        const int* __restrict__ offs,
        const int* __restrict__ sorted_pk,
        float* __restrict__ out) {
    __shared__ float tileT[TTOK][JCH];        // [token][col], 128 KiB
    const int j0 = blockIdx.x * JCH;
    const int t0 = blockIdx.y * TTOK;
    const int jcnt = min(JCH, VOCAB - j0);    // 2048, 2048, 904
    const int tcnt = min(TTOK, VOCAB - t0);   // 16 or 8
    const int tid = threadIdx.x;

    const int begin = offs[t0];
    const int end   = offs[t0 + tcnt];
    if (begin == end) return;                 // no positions use these tokens

    // --- load tile, transposed: tileT[token][col] ---
    const int nc4   = tcnt >> 2;              // f32x4 chunks across tokens: 4 or 2
    const int csh   = (tcnt == TTOK) ? 2 : 1;
    const int cmask = nc4 - 1;
    const int total = jcnt * nc4;
    for (int idx = tid; idx < total; idx += 1024) {
        const int jr = idx >> csh;
        const int c  = idx & cmask;
        f32x4 v = *reinterpret_cast<const f32x4*>(
            W + (size_t)(j0 + jr) * VOCAB + t0 + c * 4);
        tileT[c * 4 + 0][jr] = v.x;
        tileT[c * 4 + 1][jr] = v.y;
        tileT[c * 4 + 2][jr] = v.z;
        tileT[c * 4 + 3][jr] = v.w;
    }
    __syncthreads();

    // --- broadcast write: 16 waves, one position per wave per iteration ---
    const int wid  = tid >> 6;                // 0..15
    const int lane = tid & 63;
    const int f0 = lane * 4;                  // 0..252
    const int nfull    = jcnt >> 8;           // full 256-float chunks: 8 or 3
    const int remlanes = (jcnt & 255) >> 2;   // 0 or 34

    int i = begin + wid;
    if (i >= end) return;
    int pk = sorted_pk[i];
    for (;;) {
        const int inext = i + 16;
        int pk_next = 0;
        if (inext < end) pk_next = sorted_pk[inext];   // prefetch next position

        const int p  = pk >> 13;
        const int tt = (pk & 8191) - t0;
        const float* __restrict__ srow = &tileT[tt][0];
        float* __restrict__ drow = out + (size_t)p * VOCAB + j0;
#pragma unroll
        for (int s = 0; s < 8; ++s) {
            if (s < nfull) {
                f32x4 v = *reinterpret_cast<const f32x4*>(srow + f0 + s * 256);
                __builtin_nontemporal_store(
                    v, reinterpret_cast<f32x4*>(drow + f0 + s * 256));
            }
        }
        if (lane < remlanes) {
            f32x4 v = *reinterpret_cast<const f32x4*>(srow + f0 + nfull * 256);
            __builtin_nontemporal_store(
                v, reinterpret_cast<f32x4*>(drow + f0 + nfull * 256));
        }
        if (inext >= end) break;
        i = inext;
        pk = pk_next;
    }
}

// ---------------------------------------------------------------------------
// Fallback (ws too small): direct column gather, correct but strided reads.
// ---------------------------------------------------------------------------
__global__ void gather_cols_kernel(const float* __restrict__ W,
                                   const int* __restrict__ idx,
                                   float* __restrict__ out) {
    const int p = blockIdx.x;
    const int token = idx[p];
    for (int v = threadIdx.x; v < VOCAB; v += blockDim.x)
        out[(size_t)p * VOCAB + v] = W[(size_t)v * VOCAB + token];
}

extern "C" void kernel_launch(void* const* d_in, const int* in_sizes, int n_in,
                              void* d_out, int out_size, void* d_ws, size_t ws_size,
                              hipStream_t stream) {
    const int*   x = (const int*)d_in[0];     // [B*T] token ids
    const float* W = (const float*)d_in[1];   // [VOCAB, VOCAB] fp32
    float* out = (float*)d_out;               // [B*T, VOCAB] fp32
    const int npos = in_sizes[0];             // 32768

    // ws layout: counts[V] | cursor[V] | offs[V+1] | sorted_pk[npos]
    int* counts = (int*)d_ws;
    int* cursor = counts + VOCAB;
    int* offs   = cursor + VOCAB;
    int* sorted = offs + VOCAB + 1;
    const size_t need = (size_t)(3 * VOCAB + 1 + npos) * sizeof(int);

    if (ws_size >= need) {
        zero_kernel<<<(2 * VOCAB + 255) / 256, 256, 0, stream>>>(counts, 2 * VOCAB);
        hist_kernel<<<(npos + 255) / 256, 256, 0, stream>>>(x, counts, npos);
        scan_kernel<<<1, 1024, 0, stream>>>(counts, offs);
        scatter_kernel<<<(npos + 255) / 256, 256, 0, stream>>>(x, offs, cursor, sorted, npos);
        dim3 grid((VOCAB + JCH - 1) / JCH, (VOCAB + TTOK - 1) / TTOK);  // 3 x 313
        fused_gather_kernel<<<grid, 1024, 0, stream>>>(W, offs, sorted, out);
    } else {
        gather_cols_kernel<<<npos, 256, 0, stream>>>(W, x, out);
    }
}